// Round 5
// baseline (537.704 us; speedup 1.0000x reference)
//
#include <hip/hip_runtime.h>
#include <math.h>

// Problem constants
#define NROWS 16384   // 32*512
#define H     768
#define KEXP  6912    // 768 (silu*base_w) + 768*8 (bases*spline_w*scaler)
#define NSILU 12      // silu k-chunks of 64
#define NCHUNK 108    // KEXP/64

typedef __attribute__((ext_vector_type(8))) short  bhalf8;
typedef __attribute__((ext_vector_type(4))) float  floatx4;

__device__ __forceinline__ unsigned short f2bf(float f) {
    unsigned int u = __float_as_uint(f);
    u = (u + 0x7FFFu + ((u >> 16) & 1u)) >> 16;   // RNE
    return (unsigned short)u;
}
__device__ __forceinline__ float bf2f(unsigned short h) {
    return __uint_as_float(((unsigned int)h) << 16);
}
__device__ __forceinline__ unsigned int pack2(unsigned short a, unsigned short b) {
    return (unsigned int)a | ((unsigned int)b << 16);
}
__device__ __forceinline__ float silu_f(float x) { return x / (1.0f + __expf(-x)); }
__device__ __forceinline__ float gelu_exact(float x) {
    return 0.5f * x * (1.0f + erff(x * 0.70710678118654752f));
}

// Closed-form cubic B-spline bases on uniform knots g[j] = (j-3)*0.4 - 1.
// (round-4-verified: identical absmax to Cox-de-Boor recursion)
__device__ __forceinline__ void kan_bases(float x, float* __restrict__ b) {
    const float c6 = 0.166666666667f;
    float u  = fmaf(x, 2.5f, 5.5f);      // (x + 2.2) / 0.4
    float fj = floorf(u);
    float t  = u - fj;                    // in [0,1)
    int  j0  = (int)fj;
    float t2 = t * t, t3 = t2 * t;
    float n0 = t3 * c6;
    float n1 = fmaf(t3, -0.5f, fmaf(t2, 0.5f, fmaf(t, 0.5f, c6)));
    float n2 = fmaf(t3, 0.5f, fmaf(t2, -1.0f, 0.666666666667f));
    float omt = 1.0f - t;
    float n3 = omt * omt * omt * c6;
#pragma unroll
    for (int c = 0; c < 8; ++c) {
        int d = j0 - c;
        float v = (d == 0) ? n0 : 0.0f;
        v = (d == 1) ? n1 : v;
        v = (d == 2) ? n2 : v;
        v = (d == 3) ? n3 : v;
        b[c] = v;
    }
}

// ---- Build W' bf16 [768][6912]: row n = [ bw1[n][:] | sw1[n][i][c]*sc1[n][i] ]
__global__ __launch_bounds__(256) void prep_w1(
    const float* __restrict__ bw, const float* __restrict__ sw,
    const float* __restrict__ sc, unsigned short* __restrict__ wp)
{
    const int n = blockIdx.x, t = threadIdx.x;
    const float* bwr = bw + (size_t)n * H;
    unsigned short* out = wp + (size_t)n * KEXP;
    for (int k = t; k < H; k += 256) out[k] = f2bf(bwr[k]);
#pragma unroll
    for (int p = 0; p < 3; ++p) {
        int i = t + p * 256;
        float s = sc[(size_t)n * H + i];
        const float4* swp = (const float4*)(sw + ((size_t)n * H + i) * 8);
        float4 w0 = swp[0], w1 = swp[1];
        uint4 pk;
        pk.x = pack2(f2bf(w0.x * s), f2bf(w0.y * s));
        pk.y = pack2(f2bf(w0.z * s), f2bf(w0.w * s));
        pk.z = pack2(f2bf(w1.x * s), f2bf(w1.y * s));
        pk.w = pack2(f2bf(w1.z * s), f2bf(w1.w * s));
        *(uint4*)(out + H + (size_t)i * 8) = pk;
    }
}

// ---- Layer 1: fused feature-expansion + bf16 MFMA GEMM + GELU epilogue.
// A staged inline (closed-form bases, 6x recompute ~45us chip-wide, overlaps
// with MFMA per m114); B via global_load_lds w=16. 128x128 tile, BK=64,
// XOR-granule swizzle (0 bank conflicts r2-r4), XCD-aware block swizzle (r4:
// fetch 688->155MB). Stores u = gelu(h) bf16 so kan2 skips erf.
__global__ __launch_bounds__(256, 3) void kan1_fused(
    const float* __restrict__ x, const unsigned short* __restrict__ wp,
    unsigned short* __restrict__ l1)
{
    __shared__ __align__(16) unsigned short sA[128 * 64];
    __shared__ __align__(16) unsigned short sB[128 * 64];
    const int b = blockIdx.x;          // 0..767
    const int xcd = b & 7, sw_ = b >> 3;
    const int rowT = xcd * 16 + sw_ / 6;
    const int colT = sw_ % 6;
    const int rowBase = rowT * 128, colBase = colT * 128;

    const int t = threadIdx.x;
    const int lane = t & 63, wv = t >> 6;
    const int quad = lane >> 4, lm = lane & 15;
    const int wr = wv & 1, wc = wv >> 1;
    const int p7 = lm & 7;

    floatx4 acc[4][4] = {};
    int aoff[4], boff[4], goff[2];
#pragma unroll
    for (int im = 0; im < 4; ++im) aoff[im] = (wr * 64 + im * 16 + lm) * 64;
#pragma unroll
    for (int in_ = 0; in_ < 4; ++in_) boff[in_] = (wc * 64 + in_ * 16 + lm) * 64;
#pragma unroll
    for (int kk = 0; kk < 2; ++kk) goff[kk] = ((kk * 4 + quad) ^ p7) * 8;

    const int br_off = lane >> 3;
    const int bg_slot = lane & 7;

#pragma unroll 1
    for (int kc = 0; kc < NCHUNK; ++kc) {
        // ---- stage A: inline features -> LDS (swizzled) ----
        if (kc < NSILU) {
            const int i0 = kc * 64;
#pragma unroll
            for (int q = 0; q < 4; ++q) {
                int e = t + 256 * q;
                int r = e >> 3, gc = e & 7;
                const float* xp = x + (size_t)(rowBase + r) * H + i0 + gc * 8;
                float4 v0 = *(const float4*)xp, v1 = *(const float4*)(xp + 4);
                uint4 pk;
                pk.x = pack2(f2bf(silu_f(v0.x)), f2bf(silu_f(v0.y)));
                pk.y = pack2(f2bf(silu_f(v0.z)), f2bf(silu_f(v0.w)));
                pk.z = pack2(f2bf(silu_f(v1.x)), f2bf(silu_f(v1.y)));
                pk.w = pack2(f2bf(silu_f(v1.z)), f2bf(silu_f(v1.w)));
                *(uint4*)&sA[(r * 8 + (gc ^ (r & 7))) * 8] = pk;
            }
        } else {
            const int i0 = (kc - NSILU) * 8;
#pragma unroll
            for (int q = 0; q < 4; ++q) {
                int e = t + 256 * q;
                int r = e >> 3, c8 = e & 7;
                float xv = x[(size_t)(rowBase + r) * H + i0 + c8];
                float bb[8];
                kan_bases(xv, bb);
                uint4 pk;
                pk.x = pack2(f2bf(bb[0]), f2bf(bb[1]));
                pk.y = pack2(f2bf(bb[2]), f2bf(bb[3]));
                pk.z = pack2(f2bf(bb[4]), f2bf(bb[5]));
                pk.w = pack2(f2bf(bb[6]), f2bf(bb[7]));
                *(uint4*)&sA[(r * 8 + (c8 ^ (r & 7))) * 8] = pk;
            }
        }
        // ---- stage B: W' -> LDS via global_load_lds (source-swizzled) ----
#pragma unroll
        for (int p = 0; p < 4; ++p) {
            int sseg = wv * 4 + p;
            int r = sseg * 8 + br_off;
            int g = bg_slot ^ (r & 7);
            const unsigned short* gp = wp + (size_t)(colBase + r) * KEXP + kc * 64 + g * 8;
            __builtin_amdgcn_global_load_lds(
                (const __attribute__((address_space(1))) void*)gp,
                (__attribute__((address_space(3))) void*)(sB + sseg * 512), 16, 0, 0);
        }
        __syncthreads();
#pragma unroll
        for (int kk = 0; kk < 2; ++kk) {
            bhalf8 af[4], bf[4];
#pragma unroll
            for (int im = 0; im < 4; ++im) af[im] = *(const bhalf8*)&sA[aoff[im] + goff[kk]];
#pragma unroll
            for (int in_ = 0; in_ < 4; ++in_) bf[in_] = *(const bhalf8*)&sB[boff[in_] + goff[kk]];
#pragma unroll
            for (int im = 0; im < 4; ++im)
#pragma unroll
                for (int in_ = 0; in_ < 4; ++in_)
                    acc[im][in_] = __builtin_amdgcn_mfma_f32_16x16x32_bf16(
                        af[im], bf[in_], acc[im][in_], 0, 0, 0);
        }
        __syncthreads();
    }
    // ---- epilogue: apply exact GELU, store u bf16 ----
#pragma unroll
    for (int im = 0; im < 4; ++im) {
#pragma unroll
        for (int in_ = 0; in_ < 4; ++in_) {
            int col = colBase + wc * 64 + in_ * 16 + lm;
            size_t rbase = (size_t)(rowBase + wr * 64 + im * 16 + quad * 4);
#pragma unroll
            for (int reg = 0; reg < 4; ++reg)
                l1[(rbase + reg) * H + col] = f2bf(gelu_exact(acc[im][in_][reg]));
        }
    }
}

// ---- Layer 2: features of u + (768*9 -> 2) reduction, one wave per row ----
__global__ __launch_bounds__(256) void kan2_kernel(
    const unsigned short* __restrict__ l1, const float* __restrict__ bw,
    const float* __restrict__ sw, const float* __restrict__ sc,
    float* __restrict__ out)
{
    const int lane = threadIdx.x & 63;
    const int wv = threadIdx.x >> 6;
    const int n = blockIdx.x * 4 + wv;
    float a0 = 0.f, a1 = 0.f;
#pragma unroll
    for (int ii = 0; ii < H / 64; ++ii) {
        int i = lane + ii * 64;
        float u = bf2f(l1[(size_t)n * H + i]);   // u = gelu(h), applied in kan1
        float f0 = silu_f(u);
        float bb[8];
        kan_bases(u, bb);
        float bw0 = bw[i], bw1 = bw[H + i];
        float s0 = sc[i], s1 = sc[H + i];
        const float4* p0 = (const float4*)(sw + (size_t)i * 8);
        const float4* p1 = (const float4*)(sw + (size_t)(H + i) * 8);
        float4 w00 = p0[0], w01 = p0[1];
        float4 w10 = p1[0], w11 = p1[1];
        float t0 = bb[0] * w00.x + bb[1] * w00.y + bb[2] * w00.z + bb[3] * w00.w
                 + bb[4] * w01.x + bb[5] * w01.y + bb[6] * w01.z + bb[7] * w01.w;
        float t1 = bb[0] * w10.x + bb[1] * w10.y + bb[2] * w10.z + bb[3] * w10.w
                 + bb[4] * w11.x + bb[5] * w11.y + bb[6] * w11.z + bb[7] * w11.w;
        a0 += f0 * bw0 + s0 * t0;
        a1 += f0 * bw1 + s1 * t1;
    }
#pragma unroll
    for (int off = 32; off > 0; off >>= 1) {
        a0 += __shfl_down(a0, off, 64);
        a1 += __shfl_down(a1, off, 64);
    }
    if (lane == 0) {
        out[(size_t)n * 2 + 0] = a0;
        out[(size_t)n * 2 + 1] = a1;
    }
}

extern "C" void kernel_launch(void* const* d_in, const int* in_sizes, int n_in,
                              void* d_out, int out_size, void* d_ws, size_t ws_size,
                              hipStream_t stream) {
    const float* hidden = (const float*)d_in[0];
    const float* bw1    = (const float*)d_in[1];
    const float* sw1    = (const float*)d_in[2];
    const float* sc1    = (const float*)d_in[3];
    const float* bw2    = (const float*)d_in[4];
    const float* sw2    = (const float*)d_in[5];
    const float* sc2    = (const float*)d_in[6];
    float* out = (float*)d_out;

    const size_t l1_elems = (size_t)NROWS * H;     // 25.2 MB bf16
    unsigned short* l1 = (unsigned short*)d_ws;
    unsigned short* wp = l1 + l1_elems;            // 10.6 MB bf16

    prep_w1<<<H, 256, 0, stream>>>(bw1, sw1, sc1, wp);
    kan1_fused<<<768, 256, 0, stream>>>(hidden, wp, l1);
    kan2_kernel<<<NROWS / 4, 256, 0, stream>>>(l1, bw2, sw2, sc2, out);
}